// Round 1
// baseline (565.676 us; speedup 1.0000x reference)
//
#include <hip/hip_runtime.h>

typedef __bf16 bf16;
typedef unsigned short u16;
typedef __attribute__((ext_vector_type(8))) __bf16 bf16x8;
typedef __attribute__((ext_vector_type(4))) float f32x4;

#define N_PTS 400000
#define KVOL 27

__device__ __forceinline__ f32x4 mfma16(bf16x8 a, bf16x8 b, f32x4 c) {
  return __builtin_amdgcn_mfma_f32_16x16x32_bf16(a, b, c, 0, 0, 0);
}

// ---------------- cast feats fp32 -> bf16 (vectorized 8/thread) ----------------
__global__ __launch_bounds__(256) void cast_feats_k(const float4* __restrict__ in,
                                                    bf16x8* __restrict__ out) {
  int i = blockIdx.x * 256 + threadIdx.x;   // 6,400,000 threads exactly
  float4 a = in[2 * i], b = in[2 * i + 1];
  bf16x8 v;
  v[0] = (bf16)a.x; v[1] = (bf16)a.y; v[2] = (bf16)a.z; v[3] = (bf16)a.w;
  v[4] = (bf16)b.x; v[5] = (bf16)b.y; v[6] = (bf16)b.z; v[7] = (bf16)b.w;
  out[i] = v;
}

// ---- cast + transpose + swizzle conv_w -> Wt[k][co][chunk^=co&7][8], lin_w likewise ----
__global__ __launch_bounds__(256) void cast_w_k(const float* __restrict__ conv_w,
                                                const float* __restrict__ lin_w,
                                                bf16x8* __restrict__ wt,
                                                bf16x8* __restrict__ lt) {
  int t = blockIdx.x * 256 + threadIdx.x;   // 57344 threads exactly
  if (t < KVOL * 128 * 16) {
    int k = t >> 11;
    int rem = t & 2047;
    int co = rem >> 4;
    int cp = rem & 15;
    int cl = cp ^ (co & 7);                 // logical chunk stored at position cp
    bf16x8 v;
#pragma unroll
    for (int j = 0; j < 8; ++j) {
      int ci = cl * 8 + j;
      v[j] = (bf16)conv_w[(k * 128 + ci) * 128 + co];  // transpose: Wt[co][ci]
    }
    wt[t] = v;
  } else {
    int t2 = t - KVOL * 128 * 16;           // 0..2047
    int co = t2 >> 4;
    int cp = t2 & 15;
    int cl = cp ^ (co & 7);
    bf16x8 v;
#pragma unroll
    for (int j = 0; j < 8; ++j) v[j] = (bf16)lin_w[co * 128 + cl * 8 + j];  // already [co][ci]
    lt[t2] = v;
  }
}

// ---------------- fused conv + linear + layernorm ----------------
__global__ __launch_bounds__(256, 2) void fused_k(
    const bf16* __restrict__ featsb,
    const int* __restrict__ nbr,
    const uint4* __restrict__ wt,     // swizzled, 2048 uint4 per tap
    const uint4* __restrict__ lt,     // swizzled, 2048 uint4
    const float* __restrict__ conv_b,
    const float* __restrict__ lin_b,
    const float* __restrict__ ln_g,
    const float* __restrict__ ln_b,
    float* __restrict__ out) {
  __shared__ u16 wbuf[128 * 128];     // 32 KB weights (swizzled)
  __shared__ u16 cobuf[128 * 128];    // 32 KB conv-out bf16 (swizzled)
  __shared__ int nbrbuf[128 * KVOL];  // 13.8 KB

  const int tid = threadIdx.x;
  const int lane = tid & 63;
  const int wv = tid >> 6;            // wave 0..3
  const int l15 = lane & 15;
  const int l4 = lane >> 4;           // 0..3
  const int lp = lane & 7;
  const int row0 = blockIdx.x * 128;

  for (int i = tid; i < 128 * KVOL; i += 256) nbrbuf[i] = nbr[row0 * KVOL + i];

  f32x4 acc0[8], acc1[8];
#pragma unroll
  for (int ct = 0; ct < 8; ++ct) { acc0[ct] = (f32x4)0.f; acc1[ct] = (f32x4)0.f; }

  const int rloc0 = wv * 32 + l15;    // this lane's A-row (row group 0)
  const int rloc1 = rloc0 + 16;       // row group 1

  for (int k = 0; k < KVOL; ++k) {
    __syncthreads();                  // wbuf free to overwrite (covers nbrbuf ready, iter 0)
    {
      const uint4* src = wt + (size_t)k * 2048;
      uint4* dst = (uint4*)wbuf;
#pragma unroll
      for (int c = 0; c < 8; ++c) dst[c * 256 + tid] = src[c * 256 + tid];
    }
    int idx0 = nbrbuf[rloc0 * KVOL + k];
    int idx1 = nbrbuf[rloc1 * KVOL + k];
    __syncthreads();                  // wbuf ready
    const bf16* p0 = featsb + (size_t)(idx0 < 0 ? 0 : idx0) * 128 + l4 * 8;
    const bf16* p1 = featsb + (size_t)(idx1 < 0 ? 0 : idx1) * 128 + l4 * 8;
    bf16x8 z = {};
#pragma unroll
    for (int kf = 0; kf < 4; ++kf) {
      bf16x8 a0 = *(const bf16x8*)(p0 + kf * 32);   // A-frag: row l&15, 8 contiguous k
      bf16x8 a1 = *(const bf16x8*)(p1 + kf * 32);
      if (idx0 < 0) a0 = z;
      if (idx1 < 0) a1 = z;
      const int chunk = (kf * 4 + l4) ^ lp;         // swizzled B chunk (co&7 == lp)
#pragma unroll
      for (int ct = 0; ct < 8; ++ct) {
        bf16x8 b = *(const bf16x8*)((const u16*)wbuf + (ct * 16 + l15) * 128 + chunk * 8);
        acc0[ct] = mfma16(a0, b, acc0[ct]);
        acc1[ct] = mfma16(a1, b, acc1[ct]);
      }
    }
  }

  // ---- conv bias + cast to bf16 into cobuf (swizzled) ----
  float cbv[8];
#pragma unroll
  for (int ct = 0; ct < 8; ++ct) cbv[ct] = conv_b[ct * 16 + l15];
#pragma unroll
  for (int rg = 0; rg < 2; ++rg) {
#pragma unroll
    for (int ct = 0; ct < 8; ++ct) {
      f32x4 v = (rg == 0) ? acc0[ct] : acc1[ct];
#pragma unroll
      for (int j = 0; j < 4; ++j) {
        int r = wv * 32 + rg * 16 + l4 * 4 + j;     // C/D layout: row = l4*4 + reg
        int c = ct * 16 + l15;
        float x = v[j] + cbv[ct];
        int chunk = (c >> 3) ^ (r & 7);
        cobuf[r * 128 + chunk * 8 + (c & 7)] = __builtin_bit_cast(u16, (bf16)x);
      }
    }
  }
  __syncthreads();                    // all taps' wbuf reads + cobuf writes complete
  {
    uint4* dst = (uint4*)wbuf;
#pragma unroll
    for (int c = 0; c < 8; ++c) dst[c * 256 + tid] = lt[c * 256 + tid];
  }
  __syncthreads();                    // lin weights + cobuf ready

  // ---- linear layer: out2 = convout @ lin_w.T ----
  f32x4 acc2a[8], acc2b[8];
#pragma unroll
  for (int ct = 0; ct < 8; ++ct) { acc2a[ct] = (f32x4)0.f; acc2b[ct] = (f32x4)0.f; }
#pragma unroll
  for (int kf = 0; kf < 4; ++kf) {
    const int chunk = (kf * 4 + l4) ^ lp;           // r&7 == lp and co&7 == lp
    bf16x8 a0 = *(const bf16x8*)((const u16*)cobuf + rloc0 * 128 + chunk * 8);
    bf16x8 a1 = *(const bf16x8*)((const u16*)cobuf + rloc1 * 128 + chunk * 8);
#pragma unroll
    for (int ct = 0; ct < 8; ++ct) {
      bf16x8 b = *(const bf16x8*)((const u16*)wbuf + (ct * 16 + l15) * 128 + chunk * 8);
      acc2a[ct] = mfma16(a0, b, acc2a[ct]);
      acc2b[ct] = mfma16(a1, b, acc2b[ct]);
    }
  }

  // ---- + lin_b, LayerNorm (in-register, shfl reduce over 16-lane col group), store ----
  float lbv[8], lgv[8], lbbv[8];
#pragma unroll
  for (int ct = 0; ct < 8; ++ct) {
    int c = ct * 16 + l15;
    lbv[ct] = lin_b[c]; lgv[ct] = ln_g[c]; lbbv[ct] = ln_b[c];
  }
#pragma unroll
  for (int rg = 0; rg < 2; ++rg) {
#pragma unroll
    for (int j = 0; j < 4; ++j) {
      float s = 0.f, q = 0.f;
#pragma unroll
      for (int ct = 0; ct < 8; ++ct) {
        float x = ((rg == 0) ? acc2a[ct][j] : acc2b[ct][j]) + lbv[ct];
        s += x; q += x * x;
      }
#pragma unroll
      for (int m = 1; m <= 8; m <<= 1) {   // reduce across lanes l4*16 + 0..15
        s += __shfl_xor(s, m, 64);
        q += __shfl_xor(q, m, 64);
      }
      float mu = s * (1.f / 128.f);
      float var = q * (1.f / 128.f) - mu * mu;
      float rstd = rsqrtf(var + 1e-5f);
      int r = row0 + wv * 32 + rg * 16 + l4 * 4 + j;
#pragma unroll
      for (int ct = 0; ct < 8; ++ct) {
        float x = ((rg == 0) ? acc2a[ct][j] : acc2b[ct][j]) + lbv[ct];
        out[(size_t)r * 128 + ct * 16 + l15] = (x - mu) * rstd * lgv[ct] + lbbv[ct];
      }
    }
  }
}

extern "C" void kernel_launch(void* const* d_in, const int* in_sizes, int n_in,
                              void* d_out, int out_size, void* d_ws, size_t ws_size,
                              hipStream_t stream) {
  const float* feats  = (const float*)d_in[0];
  const int*   nbr    = (const int*)d_in[1];
  const float* conv_w = (const float*)d_in[2];
  const float* conv_b = (const float*)d_in[3];
  const float* lin_w  = (const float*)d_in[4];
  const float* lin_b  = (const float*)d_in[5];
  const float* ln_g   = (const float*)d_in[6];
  const float* ln_b   = (const float*)d_in[7];
  float* out = (float*)d_out;

  bf16* featsb = (bf16*)d_ws;                       // 102,400,000 B
  bf16* wt = featsb + (size_t)N_PTS * 128;          // 884,736 B
  bf16* lt = wt + (size_t)KVOL * 128 * 128;         // 32,768 B

  cast_feats_k<<<25000, 256, 0, stream>>>((const float4*)feats, (bf16x8*)featsb);
  cast_w_k<<<224, 256, 0, stream>>>(conv_w, lin_w, (bf16x8*)wt, (bf16x8*)lt);
  fused_k<<<3125, 256, 0, stream>>>(featsb, nbr, (const uint4*)wt, (const uint4*)lt,
                                    conv_b, lin_b, ln_g, ln_b, out);
}

// Round 2
// 434.229 us; speedup vs baseline: 1.3027x; 1.3027x over previous
//
#include <hip/hip_runtime.h>

typedef __bf16 bf16;
typedef unsigned short u16;
typedef __attribute__((ext_vector_type(8))) __bf16 bf16x8;
typedef __attribute__((ext_vector_type(4))) float f32x4;
typedef const __attribute__((address_space(1))) char gchar;

#define N_PTS 400000
#define KVOL 27
#define SCHED0() __builtin_amdgcn_sched_barrier(0)

__device__ __forceinline__ f32x4 mfma16(bf16x8 a, bf16x8 b, f32x4 c) {
  return __builtin_amdgcn_mfma_f32_16x16x32_bf16(a, b, c, 0, 0, 0);
}

// ---------------- cast feats fp32 -> bf16 (vectorized 8/thread) ----------------
__global__ __launch_bounds__(256) void cast_feats_k(const float4* __restrict__ in,
                                                    bf16x8* __restrict__ out) {
  int i = blockIdx.x * 256 + threadIdx.x;   // 6,400,000 threads exactly
  float4 a = in[2 * i], b = in[2 * i + 1];
  bf16x8 v;
  v[0] = (bf16)a.x; v[1] = (bf16)a.y; v[2] = (bf16)a.z; v[3] = (bf16)a.w;
  v[4] = (bf16)b.x; v[5] = (bf16)b.y; v[6] = (bf16)b.z; v[7] = (bf16)b.w;
  out[i] = v;
}

// ---- conv_w -> swizzled-transposed bf16 Wt[k][co][cp][8]; lin_w -> plain bf16; zrow ----
__global__ __launch_bounds__(256) void cast_w_k(const float* __restrict__ conv_w,
                                                const float* __restrict__ lin_w,
                                                bf16x8* __restrict__ wt,
                                                bf16x8* __restrict__ lt,
                                                bf16x8* __restrict__ zrow) {
  int t = blockIdx.x * 256 + threadIdx.x;   // 57600 threads, 57360 used
  if (t < KVOL * 128 * 16) {
    int k = t >> 11;
    int rem = t & 2047;
    int co = rem >> 4;
    int cp = rem & 15;
    int cl = cp ^ (co & 7);                 // logical chunk stored at position cp
    bf16x8 v;
#pragma unroll
    for (int j = 0; j < 8; ++j) {
      int ci = cl * 8 + j;
      v[j] = (bf16)conv_w[(k * 128 + ci) * 128 + co];  // transpose: Wt[co][ci]
    }
    wt[t] = v;
  } else if (t < KVOL * 128 * 16 + 2048) {
    int t2 = t - KVOL * 128 * 16;
    bf16x8 v;
#pragma unroll
    for (int j = 0; j < 8; ++j) v[j] = (bf16)lin_w[t2 * 8 + j];  // [co][ci] plain
    lt[t2] = v;
  } else if (t < KVOL * 128 * 16 + 2048 + 16) {
    bf16x8 v = {};
    zrow[t - (KVOL * 128 * 16 + 2048)] = v;
  }
}

// ---------------- fused conv(dbuf pipeline) + linear + layernorm ----------------
__global__ __launch_bounds__(256, 2) void fused_k(
    const bf16* __restrict__ featsb,
    const int* __restrict__ nbr,
    const bf16* __restrict__ wt,      // swizzled [27][128][128]
    const bf16* __restrict__ lt,      // plain [128][128]
    const bf16* __restrict__ zrow,    // 128 zeros
    const float* __restrict__ conv_b,
    const float* __restrict__ lin_b,
    const float* __restrict__ ln_g,
    const float* __restrict__ ln_b,
    float* __restrict__ out) {
  __shared__ __align__(16) u16 wdb[2][16384];   // 2 x 32 KB W double-buffer

  const int tid = threadIdx.x;
  const int lane = tid & 63;
  const int wv = tid >> 6;
  const int l15 = lane & 15;
  const int l4 = lane >> 4;
  const int lp = lane & 7;

  // bijective XCD-aware swizzle (m204)
  const int nwg = gridDim.x;
  const int bid0 = blockIdx.x;
  const int q = nwg >> 3, r8 = nwg & 7;
  const int xcd = bid0 & 7, lo = bid0 >> 3;
  const int bid = (xcd < r8 ? xcd * (q + 1) : r8 * (q + 1) + (xcd - r8) * q) + lo;

  const int row0 = bid * 256;
  const int rb = row0 + wv * 64 + l15;  // + rg*16 -> this lane's rows
  const int aoff = l4 * 16;             // byte offset of this lane's A-frag slice in a row

  // ---- prologue: stage W(0) -> wdb[0]; load idx(0),(1); gather A(0) ----
  {
    const char* g = (const char*)wt + (size_t)tid * 16;
    char* l = (char*)(&wdb[0][0]) + wv * 1024;
#pragma unroll
    for (int c = 0; c < 8; ++c)
      __builtin_amdgcn_global_load_lds(
          (const __attribute__((address_space(1))) void*)(g + c * 4096),
          (__attribute__((address_space(3))) void*)(l + c * 4096), 16, 0, 0);
  }
  int idx_nxt[4];
  int idx_t0[4];
#pragma unroll
  for (int rg = 0; rg < 4; ++rg) {
    int r = rb + rg * 16;
    int rr = r < N_PTS ? r : N_PTS - 1;
    int v0 = nbr[(size_t)rr * KVOL + 0];
    int v1 = nbr[(size_t)rr * KVOL + 1];
    idx_t0[rg] = r < N_PTS ? v0 : -1;
    idx_nxt[rg] = r < N_PTS ? v1 : -1;
  }
  bf16x8 a[4][4];
#pragma unroll
  for (int rg = 0; rg < 4; ++rg) {
    gchar* base = (idx_t0[rg] < 0)
                      ? (gchar*)zrow
                      : (gchar*)featsb + (size_t)idx_t0[rg] * 256;
    base += aoff;
#pragma unroll
    for (int kf = 0; kf < 4; ++kf) a[rg][kf] = *(const __attribute__((address_space(1))) bf16x8*)(base + kf * 64);
  }
  f32x4 acc[4][8];
#pragma unroll
  for (int rg = 0; rg < 4; ++rg)
#pragma unroll
    for (int ct = 0; ct < 8; ++ct) acc[rg][ct] = (f32x4)0.f;

  SCHED0();
  asm volatile("s_waitcnt vmcnt(0)" ::: "memory");
  SCHED0();
  __builtin_amdgcn_s_barrier();
  SCHED0();

  // ---- main pipelined loop over taps ----
  int cur = 0;
  for (int t = 0; t < KVOL; ++t) {
    // a) stage W(t+1) (clamped) into wdb[cur^1]  -- 8 global_load_lds
    {
      int tn = t + 1 < KVOL ? t + 1 : KVOL - 1;
      const char* g = (const char*)wt + (size_t)tn * 32768 + (size_t)tid * 16;
      char* l = (char*)(&wdb[cur ^ 1][0]) + wv * 1024;
#pragma unroll
      for (int c = 0; c < 8; ++c)
        __builtin_amdgcn_global_load_lds(
            (const __attribute__((address_space(1))) void*)(g + c * 4096),
            (__attribute__((address_space(3))) void*)(l + c * 4096), 16, 0, 0);
    }
    // b) A(t+1) base pointers from idx_nxt (loaded last iter)
    gchar* nb[4];
#pragma unroll
    for (int rg = 0; rg < 4; ++rg) {
      gchar* base = (idx_nxt[rg] < 0)
                        ? (gchar*)zrow
                        : (gchar*)featsb + (size_t)idx_nxt[rg] * 256;
      nb[rg] = base + aoff;
    }
    // c) refill idx_nxt with idx(t+2)  -- 4 loads (anti-dep only, no wait here)
    {
      int k2 = t + 2 < KVOL ? t + 2 : KVOL - 1;
#pragma unroll
      for (int rg = 0; rg < 4; ++rg) {
        int r = rb + rg * 16;
        int rr = r < N_PTS ? r : N_PTS - 1;
        int v = nbr[(size_t)rr * KVOL + k2];
        idx_nxt[rg] = r < N_PTS ? v : -1;
      }
    }
    // d) counted wait: W(t)'s 8 loads have exactly 32 younger VMEM ops
    SCHED0();
    asm volatile("s_waitcnt vmcnt(32)" ::: "memory");
    SCHED0();
    __builtin_amdgcn_s_barrier();
    SCHED0();
    // e) MFMA phase; after last use of a[*][kf], issue next-tap gather into it
    const u16* wb = &wdb[cur][0];
#pragma unroll
    for (int kf = 0; kf < 4; ++kf) {
      const int chunk = (kf * 4 + l4) ^ lp;
      const u16* bp = wb + l15 * 128 + chunk * 8;
#pragma unroll
      for (int ct = 0; ct < 8; ++ct) {
        bf16x8 b = *(const bf16x8*)(bp + ct * 2048);
#pragma unroll
        for (int rg = 0; rg < 4; ++rg)
          acc[rg][ct] = mfma16(a[rg][kf], b, acc[rg][ct]);
      }
#pragma unroll
      for (int rg = 0; rg < 4; ++rg)
        a[rg][kf] = *(const __attribute__((address_space(1))) bf16x8*)(nb[rg] + kf * 64);
    }
    // f) barrier: all waves done reading wdb[cur] before next iter stages into it
    SCHED0();
    __builtin_amdgcn_s_barrier();
    SCHED0();
    cur ^= 1;
  }

  // ---- drain stray W(27) stage writes before reusing wdb as cobuf ----
  SCHED0();
  asm volatile("s_waitcnt vmcnt(0)" ::: "memory");
  SCHED0();
  __builtin_amdgcn_s_barrier();
  SCHED0();

  // ---- conv bias + cast bf16 -> cobuf (swizzled), aliased onto wdb ----
  u16* cobuf = &wdb[0][0];
  float cb[8];
#pragma unroll
  for (int ct = 0; ct < 8; ++ct) cb[ct] = conv_b[ct * 16 + l15];
#pragma unroll
  for (int rg = 0; rg < 4; ++rg) {
#pragma unroll
    for (int ct = 0; ct < 8; ++ct) {
#pragma unroll
      for (int j = 0; j < 4; ++j) {
        int rl = wv * 64 + rg * 16 + l4 * 4 + j;   // C/D layout: row = l4*4 + reg
        int c = ct * 16 + l15;
        float x = acc[rg][ct][j] + cb[ct];
        int chunk = (c >> 3) ^ (rl & 7);
        cobuf[rl * 128 + chunk * 8 + (c & 7)] = __builtin_bit_cast(u16, (bf16)x);
      }
    }
  }
  SCHED0();
  asm volatile("s_waitcnt lgkmcnt(0)" ::: "memory");
  SCHED0();
  __builtin_amdgcn_s_barrier();
  SCHED0();

  // ---- linear layer: A from cobuf (LDS), B from lt (L2-hot global) ----
  f32x4 acc2[4][8];
#pragma unroll
  for (int rg = 0; rg < 4; ++rg)
#pragma unroll
    for (int ct = 0; ct < 8; ++ct) acc2[rg][ct] = (f32x4)0.f;
#pragma unroll
  for (int kf = 0; kf < 4; ++kf) {
    const int chunk = (kf * 4 + l4) ^ lp;
    bf16x8 av[4];
#pragma unroll
    for (int rg = 0; rg < 4; ++rg)
      av[rg] = *(const bf16x8*)(cobuf + (wv * 64 + rg * 16 + l15) * 128 + chunk * 8);
#pragma unroll
    for (int ct = 0; ct < 8; ++ct) {
      bf16x8 b = *(const bf16x8*)(lt + (ct * 16 + l15) * 128 + (kf * 4 + l4) * 8);
#pragma unroll
      for (int rg = 0; rg < 4; ++rg)
        acc2[rg][ct] = mfma16(av[rg], b, acc2[rg][ct]);
    }
  }

  // ---- + lin_b, LayerNorm (shfl reduce over 16-lane groups), guarded store ----
  float lb[8], lg[8], lbv[8];
#pragma unroll
  for (int ct = 0; ct < 8; ++ct) {
    int c = ct * 16 + l15;
    lb[ct] = lin_b[c]; lg[ct] = ln_g[c]; lbv[ct] = ln_b[c];
  }
#pragma unroll
  for (int rg = 0; rg < 4; ++rg) {
#pragma unroll
    for (int j = 0; j < 4; ++j) {
      float s = 0.f, qq = 0.f;
#pragma unroll
      for (int ct = 0; ct < 8; ++ct) {
        float x = acc2[rg][ct][j] + lb[ct];
        s += x; qq += x * x;
      }
#pragma unroll
      for (int m = 1; m <= 8; m <<= 1) {
        s += __shfl_xor(s, m, 64);
        qq += __shfl_xor(qq, m, 64);
      }
      float mu = s * (1.f / 128.f);
      float var = qq * (1.f / 128.f) - mu * mu;
      float rstd = rsqrtf(var + 1e-5f);
      int r = row0 + wv * 64 + rg * 16 + l4 * 4 + j;
      if (r < N_PTS) {
#pragma unroll
        for (int ct = 0; ct < 8; ++ct) {
          float x = acc2[rg][ct][j] + lb[ct];
          out[(size_t)r * 128 + ct * 16 + l15] = (x - mu) * rstd * lg[ct] + lbv[ct];
        }
      }
    }
  }
}

extern "C" void kernel_launch(void* const* d_in, const int* in_sizes, int n_in,
                              void* d_out, int out_size, void* d_ws, size_t ws_size,
                              hipStream_t stream) {
  const float* feats  = (const float*)d_in[0];
  const int*   nbr    = (const int*)d_in[1];
  const float* conv_w = (const float*)d_in[2];
  const float* conv_b = (const float*)d_in[3];
  const float* lin_w  = (const float*)d_in[4];
  const float* lin_b  = (const float*)d_in[5];
  const float* ln_g   = (const float*)d_in[6];
  const float* ln_b   = (const float*)d_in[7];
  float* out = (float*)d_out;

  bf16* featsb = (bf16*)d_ws;                       // 102,400,000 B
  bf16* wt = featsb + (size_t)N_PTS * 128;          // 884,736 B (swizzled)
  bf16* lt = wt + (size_t)KVOL * 128 * 128;         // 32,768 B
  bf16* zrow = lt + (size_t)128 * 128;              // 256 B zeros

  cast_feats_k<<<25000, 256, 0, stream>>>((const float4*)feats, (bf16x8*)featsb);
  cast_w_k<<<225, 256, 0, stream>>>(conv_w, lin_w, (bf16x8*)wt, (bf16x8*)lt, (bf16x8*)zrow);
  fused_k<<<1563, 256, 0, stream>>>(featsb, nbr, wt, lt, zrow,
                                    conv_b, lin_b, ln_g, ln_b, out);
}